// Round 12
// baseline (195.138 us; speedup 1.0000x reference)
//
#include <hip/hip_runtime.h>
#include <hip/hip_fp16.h>

// TrigHashGrid: B=1048576, IN_DIM=3, M=3, N=16, C=2, W=1000, A=-0.75
// R16 = R15 resubmit (previous round was an infra failure, no data).
// R15: paired-iteration schedule + ds_read2 pair fusion.
// R14 (drop nt) won: stores now absorbed by L2/L3. Remaining budget: LDS
// tap gather is the largest consumer (8x b32/thread-iter + 20.6K conflict
// cyc/CU) and VGPR has sat at 24-28 all session -- the compiler serializes
// each iteration's chain with minimal live state (this is why R8's source
// pipeline collapsed to null). Fix both structurally:
//  - two b's (A,B) per body; hand order: loadA+B -> stagesA -> issue A taps
//    -> stagesB (covers A's LDS latency) -> issue B taps -> interp/store A
//    (counted lgkmcnt, B in flight) -> interp/store B. Live peak ~55 VGPR
//    <= 64 cap: compiler must keep both chains in flight.
//  - taps read as 2x 8B pair-loads (memcpy, 4B-aligned -> ds_read2_b32):
//    LDS instruction count halves with zero layout change.
// Math identical to R14 -> absmax 0.004394531 unchanged.

constexpr float A_C = -0.75f;

#define BLK 1024
#define WPAD 1004            // 2 + 1000 + 2 positions, one __half2 each

typedef float f32x4 __attribute__((ext_vector_type(4)));

struct Stage { __half2 w0, w1, w2, w3; int ofs; };

__device__ __forceinline__ Stage mk_stage(
    float x0, float x1, float x2,
    const float* Ga, const float* Gb, const float* Gc, const float* Hh)
{
    float p = 1.0f;
#pragma unroll
    for (int m = 0; m < 3; ++m) {
        // G,H prescaled by 1/2pi: rev directly; v_sin_f32 takes revolutions.
        float rev = fmaf(x0, Ga[m], fmaf(x1, Gb[m], fmaf(x2, Gc[m], Hh[m])));
        rev = __builtin_amdgcn_fractf(rev);
        p *= __builtin_amdgcn_sinf(rev);
    }
    float ix = fmaf(p, 500.0f, 499.5f);       // [-0.5, 999.5]
    float xf = floorf(ix);
    float t  = ix - xf;
    float xfc = fminf(fmaxf(xf, -1.0f), 999.0f);   // v_med3 insurance
    int base  = (int)xfc;

    // Factored Keys weights.
    float u  = 1.0f - t;
    float tu = t * u;
    float atu = A_C * tu;
    float w0 = atu * u;
    float w3 = atu * t;
    float w1 = fmaf(fmaf(A_C + 2.0f, t, -(A_C + 3.0f)), t * t, 1.0f);
    float w2 = 1.0f - w0 - w1 - w3;

    Stage s;
    s.w0 = __float2half2_rn(w0); s.w1 = __float2half2_rn(w1);
    s.w2 = __float2half2_rn(w2); s.w3 = __float2half2_rn(w3);
    s.ofs = base + 1;                          // padded idx >= 0
    return s;
}

struct P2 { unsigned lo, hi; };                // 8B, align 4

__device__ __forceinline__ void tap_pairs(
    const __half2* tap, __half2& t0, __half2& t1, __half2& t2, __half2& t3)
{
    // 8B loads at 4B alignment -> ds_read2_b32 (one inst per pair).
    P2 a, b;
    __builtin_memcpy(&a, tap, 8);
    __builtin_memcpy(&b, tap + 2, 8);
    t0 = __builtin_bit_cast(__half2, a.lo);
    t1 = __builtin_bit_cast(__half2, a.hi);
    t2 = __builtin_bit_cast(__half2, b.lo);
    t3 = __builtin_bit_cast(__half2, b.hi);
}

__device__ __forceinline__ float2 finish(
    const Stage& s, __half2 t0, __half2 t1, __half2 t2, __half2 t3)
{
    __half2 acc = __hmul2(t0, s.w0);
    acc = __hfma2(t1, s.w1, acc);
    acc = __hfma2(t2, s.w2, acc);
    acc = __hfma2(t3, s.w3, acc);
    return __half22float2(acc);
}

__global__ __launch_bounds__(BLK, 8)
void trig_hashgrid(const float* __restrict__ x, const float* __restrict__ grids,
                   const float* __restrict__ G, const float* __restrict__ H,
                   float* __restrict__ out)
{
    __shared__ __half2 lds[16 * WPAD];        // 64256 B -> 2 blocks/CU
    const int tid = threadIdx.x;
    const int blk = blockIdx.x;               // 0..511

    // Zero the 4 pad positions per level row (padded w {0,1,1002,1003}).
    if (tid < 64) {
        int nl = tid >> 2, j = tid & 3;
        int off = (j < 2) ? j : (WPAD - 4 + j);
        lds[nl * WPAD + off] = __floats2half2_rn(0.0f, 0.0f);
    }
    // Stage all 16 levels as packed half2(c0,c1); 64 lanes/row, coalesced.
    {
        int row = tid >> 6;                   // 0..15
        int j   = tid & 63;
        const float* gsrc = grids + row * 2000;
        __half2* ldst = lds + row * WPAD;
        for (int w = j; w < 1000; w += 64)
            ldst[w + 2] = __floats2half2_rn(gsrc[w], gsrc[1000 + w]);
    }

    const int np = tid & 7;                   // level pair: n = 2np, 2np+1
    const int g  = tid >> 3;                  // 0..127
    const int n0 = 2 * np, n1 = n0 + 1;

    // Per-pair frequencies/phases, prescaled by 1/2pi.
    constexpr float C2PI = 0.15915494309189535f;
    float Ga[2][3], Gb[2][3], Gc[2][3], Hh[2][3];
#pragma unroll
    for (int m = 0; m < 3; ++m) {
        Ga[0][m] = G[0*48 + m*16 + n0] * C2PI; Ga[1][m] = G[0*48 + m*16 + n1] * C2PI;
        Gb[0][m] = G[1*48 + m*16 + n0] * C2PI; Gb[1][m] = G[1*48 + m*16 + n1] * C2PI;
        Gc[0][m] = G[2*48 + m*16 + n0] * C2PI; Gc[1][m] = G[2*48 + m*16 + n1] * C2PI;
        Hh[0][m] = H[m*16 + n0] * C2PI;        Hh[1][m] = H[m*16 + n1] * C2PI;
    }
    __syncthreads();

    const __half2* lrow0 = &lds[n0 * WPAD];
    const __half2* lrow1 = &lds[n1 * WPAD];

    // A covers i = 0,2,..,14; B covers i = 1,3,..,15 (b stride 65536).
    const float* xpA = x + (blk * 128 + g) * 3;
    const float* xpB = xpA + 65536 * 3;
    f32x4* opA = (f32x4*)out + (blk * 128 + g) * 8 + np;
    f32x4* opB = opA + 65536 * 8;

#pragma unroll 2
    for (int it = 0; it < 8; ++it) {
        // 1. both x loads up front (independent, coalesced-broadcast)
        float a0 = xpA[0], a1 = xpA[1], a2 = xpA[2];
        float b0 = xpB[0], b1 = xpB[1], b2 = xpB[2];

        // 2. A's stages, then issue A's taps (4x ds_read2_b32)
        Stage sA0 = mk_stage(a0, a1, a2, Ga[0], Gb[0], Gc[0], Hh[0]);
        Stage sA1 = mk_stage(a0, a1, a2, Ga[1], Gb[1], Gc[1], Hh[1]);
        __half2 A00, A01, A02, A03, A10, A11, A12, A13;
        tap_pairs(lrow0 + sA0.ofs, A00, A01, A02, A03);
        tap_pairs(lrow1 + sA1.ofs, A10, A11, A12, A13);

        // 3. B's stages (~100+ cyc VALU/sin covers A's LDS latency),
        //    then issue B's taps
        Stage sB0 = mk_stage(b0, b1, b2, Ga[0], Gb[0], Gc[0], Hh[0]);
        Stage sB1 = mk_stage(b0, b1, b2, Ga[1], Gb[1], Gc[1], Hh[1]);
        __half2 B00, B01, B02, B03, B10, B11, B12, B13;
        tap_pairs(lrow0 + sB0.ofs, B00, B01, B02, B03);
        tap_pairs(lrow1 + sB1.ofs, B10, B11, B12, B13);

        // 4. interp+store A (counted lgkmcnt: B's reads stay in flight)
        float2 oA0 = finish(sA0, A00, A01, A02, A03);
        float2 oA1 = finish(sA1, A10, A11, A12, A13);
        f32x4 vA = { oA0.x, oA0.y, oA1.x, oA1.y };
        *opA = vA;

        // 5. interp+store B
        float2 oB0 = finish(sB0, B00, B01, B02, B03);
        float2 oB1 = finish(sB1, B10, B11, B12, B13);
        f32x4 vB = { oB0.x, oB0.y, oB1.x, oB1.y };
        *opB = vB;

        xpA += 2 * 65536 * 3; xpB += 2 * 65536 * 3;
        opA += 2 * 65536 * 8; opB += 2 * 65536 * 8;
    }
}

extern "C" void kernel_launch(void* const* d_in, const int* in_sizes, int n_in,
                              void* d_out, int out_size, void* d_ws, size_t ws_size,
                              hipStream_t stream) {
    const float* x     = (const float*)d_in[0];
    const float* grids = (const float*)d_in[1];
    const float* G     = (const float*)d_in[2];
    const float* H     = (const float*)d_in[3];
    float* out = (float*)d_out;
    trig_hashgrid<<<512, BLK, 0, stream>>>(x, grids, G, H, out);
}